// Round 1
// baseline (2180.502 us; speedup 1.0000x reference)
//
#include <hip/hip_runtime.h>

// HeteroLayerNorm: out = (x - mean[type]) / sqrt(var[type] + 1e-5)
// N=1e6 rows, C=128 channels, T=64 types, fp32.
//
// Plan (memory-bound, ~1.55 GB ideal traffic):
//   pass1: per-block LDS privatized per-type sum/sumsq (channel-split in 2
//          halves, 32KB LDS -> 4 blocks/CU), block partials -> d_out scratch
//   pass2: reduce partials -> mean + inv_std (64KB in d_ws)
//   pass3: normalize with float4, stats from L2

#define TT    64            // num types
#define CC    128           // channels
#define HALF  64            // channels per half (pass1 channel split)
#define HPAD  65            // padded type stride: bank = (t + c) % 32
#define NB_HALF 512         // pass1 blocks per channel-half
#define PART_FLOATS (2*TT*HALF + TT)   // s + s2 + cnt = 8256 floats per block

__global__ __launch_bounds__(256, 4) void hln_pass1(
    const float* __restrict__ x, const int* __restrict__ tv,
    float* __restrict__ part, int N)
{
    __shared__ float s1[TT*HPAD];   // [t][c] padded, 16.25 KB
    __shared__ float s2[TT*HPAD];
    __shared__ float cnt[TT];
    const int tid = threadIdx.x;
    for (int i = tid; i < TT*HPAD; i += 256) { s1[i] = 0.f; s2[i] = 0.f; }
    if (tid < TT) cnt[tid] = 0.f;
    __syncthreads();

    const int b  = blockIdx.x;          // 0..2*NB_HALF-1
    const int h  = b >> 9;              // channel half (NB_HALF == 512)
    const int bh = b & (NB_HALF - 1);
    const int lr = tid & 15;            // 16 threads per row (64 ch / float4)
    const int ro = tid >> 4;            // row offset within block tile, 0..15
    const int cg = h*HALF + lr*4;       // global channel base
    const int cl = lr*4;                // local channel base

    for (int rb = bh*16; rb < N; rb += NB_HALF*16) {
        const int row = rb + ro;
        if (row < N) {
            const int t = tv[row];
            const float4 xv = *reinterpret_cast<const float4*>(x + (size_t)row*CC + cg);
            float* ps1 = s1 + t*HPAD + cl;
            float* ps2 = s2 + t*HPAD + cl;
            atomicAdd(ps1+0, xv.x); atomicAdd(ps2+0, xv.x*xv.x);
            atomicAdd(ps1+1, xv.y); atomicAdd(ps2+1, xv.y*xv.y);
            atomicAdd(ps1+2, xv.z); atomicAdd(ps2+2, xv.z*xv.z);
            atomicAdd(ps1+3, xv.w); atomicAdd(ps2+3, xv.w*xv.w);
            if (lr == 0) atomicAdd(&cnt[t], 1.f);   // counted once per half; /2 in pass2
        }
    }
    __syncthreads();

    float* my = part + (size_t)b * PART_FLOATS;
    for (int i = tid; i < TT*HALF; i += 256) {
        const int t = i >> 6, c = i & 63;
        my[i]           = s1[t*HPAD + c];
        my[TT*HALF + i] = s2[t*HPAD + c];
    }
    if (tid < TT) my[2*TT*HALF + tid] = cnt[tid];
}

__global__ void hln_pass2(const float* __restrict__ part, float* __restrict__ stats)
{
    const int idx = blockIdx.x * blockDim.x + threadIdx.x;   // 0..TT*CC-1
    if (idx >= TT*CC) return;
    const int t   = idx >> 7;     // / 128
    const int c   = idx & 127;
    const int h   = c >> 6;
    const int cin = c & 63;

    float s = 0.f, q = 0.f;
    const float* p = part + (size_t)(h*NB_HALF) * PART_FLOATS;
    for (int b = 0; b < NB_HALF; ++b) {
        s += p[t*HALF + cin];
        q += p[TT*HALF + t*HALF + cin];
        p += PART_FLOATS;
    }
    float cn = 0.f;
    for (int b = 0; b < 2*NB_HALF; ++b)
        cn += part[(size_t)b*PART_FLOATS + 2*TT*HALF + t];
    cn *= 0.5f;                        // each row counted once per half
    cn = fmaxf(cn, 1.f);

    const float mean = s / cn;
    const float var  = fmaxf(q/cn - mean*mean, 0.f);
    const float inv  = 1.f / sqrtf(var + 1e-5f);
    stats[idx]         = mean;
    stats[TT*CC + idx] = inv;
}

__global__ __launch_bounds__(256) void hln_pass3(
    const float* __restrict__ x, const int* __restrict__ tv,
    const float* __restrict__ stats, float* __restrict__ out, int N)
{
    const int lane = threadIdx.x & 31;   // 32 threads per row (128 ch / float4)
    const int ro   = threadIdx.x >> 5;   // 0..7
    const int c4   = lane*4;
    const float* meanb = stats;
    const float* invb  = stats + TT*CC;

    for (int rb = blockIdx.x*8; rb < N; rb += gridDim.x*8) {
        const int row = rb + ro;
        if (row >= N) break;
        const int t = tv[row];
        const size_t xo = (size_t)row*CC + c4;
        const float4 xv = *reinterpret_cast<const float4*>(x + xo);
        const float4 mv = *reinterpret_cast<const float4*>(meanb + t*CC + c4);
        const float4 iv = *reinterpret_cast<const float4*>(invb  + t*CC + c4);
        float4 o;
        o.x = (xv.x - mv.x) * iv.x;
        o.y = (xv.y - mv.y) * iv.y;
        o.z = (xv.z - mv.z) * iv.z;
        o.w = (xv.w - mv.w) * iv.w;
        *reinterpret_cast<float4*>(out + xo) = o;
    }
}

extern "C" void kernel_launch(void* const* d_in, const int* in_sizes, int n_in,
                              void* d_out, int out_size, void* d_ws, size_t ws_size,
                              hipStream_t stream)
{
    const float* x  = (const float*)d_in[0];
    const int*   tv = (const int*)d_in[1];
    const int N = in_sizes[0] / CC;

    float* out   = (float*)d_out;
    float* part  = out;              // reuse d_out as partial scratch (34 MB << 512 MB)
    float* stats = (float*)d_ws;     // 64 KiB: mean[T][C] then inv_std[T][C]

    hipLaunchKernelGGL(hln_pass1, dim3(2*NB_HALF), dim3(256), 0, stream, x, tv, part, N);
    hipLaunchKernelGGL(hln_pass2, dim3((TT*CC + 255)/256), dim3(256), 0, stream, part, stats);
    hipLaunchKernelGGL(hln_pass3, dim3(2048), dim3(256), 0, stream, x, tv, stats, out, N);
}